// Round 10
// baseline (215.369 us; speedup 1.0000x reference)
//
#include <hip/hip_runtime.h>

#define Bsz 8
#define Ssz 4096
#define Dsz 128

typedef short bf16x8 __attribute__((ext_vector_type(8)));
typedef float f32x4 __attribute__((ext_vector_type(4)));
typedef float f32x16 __attribute__((ext_vector_type(16)));
typedef int i32x2 __attribute__((ext_vector_type(2)));
typedef int i32x4 __attribute__((ext_vector_type(4)));
typedef unsigned int u32;

union B8 { u32 u[4]; bf16x8 v; };

__device__ __forceinline__ u32 pkbf(float a, float b) {
  u32 ra = __float_as_uint(a) + 0x8000u;
  u32 rb = __float_as_uint(b) + 0x8000u;
  return __builtin_amdgcn_perm(rb, ra, 0x07060302u);
}
__device__ __forceinline__ short f2bf(float f) {
  u32 r = __float_as_uint(f) + 0x8000u;
  return (short)(r >> 16);
}

__device__ __forceinline__ void gll16(const void* g, void* l) {
  __builtin_amdgcn_global_load_lds((const __attribute__((address_space(1))) void*)g,
                                   (__attribute__((address_space(3))) void*)l, 16, 0, 0);
}

// Staged Q/K layout (bf16), per 64-row tile (16KB): [gd 0..15][s 0..63][8 d].
// V plain row-major [s][d].

// ---------------- Projection (R9 structure; also zeroes d_out) ----------------
__global__ __launch_bounds__(256, 2) void proj_kernel(
    const float* __restrict__ x, const float* __restrict__ wsrc,
    short* __restrict__ Qs, short* __restrict__ Ks, short* __restrict__ Vp,
    float* __restrict__ out0) {
  __shared__ short xb[64 * 136];  // 17.4KB
  __shared__ short ob[8192];      // 16KB output assembly

  const int rb = blockIdx.x;
  const int t = threadIdx.x;
  const int wv = t >> 6, lane = t & 63, l31 = lane & 31, h = lane >> 5;

  if (rb < 4) out0[rb * 256 + t] = 0.f;  // zero d_out for gemv atomics

  // coalesced X tile load: 64 rows x 128 f32 = 2048 float4
  {
    const float* xsrc = x + (size_t)rb * 64 * Dsz;
    #pragma unroll
    for (int p = 0; p < 8; ++p) {
      int idx4 = p * 256 + t;
      int row = idx4 >> 5;
      int c4 = (idx4 & 31) << 2;
      f32x4 v = *(const f32x4*)&xsrc[idx4 * 4];
      i32x2 pr;
      pr[0] = pkbf(v[0], v[1]);
      pr[1] = pkbf(v[2], v[3]);
      *(i32x2*)&xb[row * 136 + c4] = pr;
    }
  }
  __syncthreads();

  bf16x8 xf[2][8];  // lane = s row (l31), k = d = c*16 + 8h + j
  #pragma unroll
  for (int st = 0; st < 2; ++st)
    #pragma unroll
    for (int c = 0; c < 8; ++c)
      xf[st][c] = *(const bf16x8*)&xb[(st * 32 + l31) * 136 + c * 16 + 8 * h];

  for (int mat = 0; mat < 3; ++mat) {
    const float* wm = wsrc + (size_t)mat * Dsz * Dsz;
    const float scale = (mat == 0) ? 1.44269504088896340736f : 1.0f;  // log2e in Wq
    bf16x8 wf[8];  // lane = e (wv*32+l31), k = d
    #pragma unroll
    for (int c = 0; c < 8; ++c) {
      const float* p = wm + (size_t)(c * 16 + 8 * h) * Dsz + wv * 32 + l31;
      B8 tmp;
      #pragma unroll
      for (int j = 0; j < 4; ++j)
        tmp.u[j] = pkbf(p[(2 * j) * Dsz] * scale, p[(2 * j + 1) * Dsz] * scale);
      wf[c] = tmp.v;
    }

    if (mat < 2) {
      // C^T[e][s] -> staged [ge][s][8e]
      #pragma unroll
      for (int st = 0; st < 2; ++st) {
        f32x16 acc = {};
        #pragma unroll
        for (int c = 0; c < 8; ++c)
          acc = __builtin_amdgcn_mfma_f32_32x32x16_bf16(wf[c], xf[st][c], acc, 0, 0, 0);
        if (st == 0) __syncthreads();
        #pragma unroll
        for (int g = 0; g < 4; ++g) {
          int e0 = wv * 32 + 8 * g + 4 * h;
          int s = st * 32 + l31;
          i32x2 pr;
          pr[0] = pkbf(acc[4 * g + 0], acc[4 * g + 1]);
          pr[1] = pkbf(acc[4 * g + 2], acc[4 * g + 3]);
          *(i32x2*)&ob[(e0 >> 3) * 512 + s * 8 + (e0 & 7)] = pr;
        }
      }
    } else {
      // C[s][e] -> row-major ob[s][e]
      #pragma unroll
      for (int st = 0; st < 2; ++st) {
        f32x16 acc = {};
        #pragma unroll
        for (int c = 0; c < 8; ++c)
          acc = __builtin_amdgcn_mfma_f32_32x32x16_bf16(xf[st][c], wf[c], acc, 0, 0, 0);
        if (st == 0) __syncthreads();
        int e = wv * 32 + l31;
        #pragma unroll
        for (int r = 0; r < 16; ++r) {
          int s = st * 32 + (r & 3) + 8 * (r >> 2) + 4 * h;
          ob[s * 128 + e] = f2bf(acc[r]);
        }
      }
    }
    __syncthreads();
    short* dst = (mat == 0 ? Qs : mat == 1 ? Ks : Vp) + (size_t)rb * 8192;
    #pragma unroll
    for (int p = 0; p < 4; ++p)
      *(i32x4*)&dst[(p * 256 + t) * 8] = *(const i32x4*)&ob[(p * 256 + t) * 8];
  }
}

// ---------------- Phase A: softmax denominators ----------------
// grid (8 b, 8 qt, 8 kt) = 512 blocks, 512 thr (8 waves) @ 2 blocks/CU = 16 waves/CU.
// q-tile 512 (wave owns 64 q), k-range 512, 128-k chunks x 4 iters, double-buffered.
__global__ __launch_bounds__(512, 4) void lsum_kernel(
    const short* __restrict__ Qs, const short* __restrict__ Ks,
    float* __restrict__ lpart) {
  __shared__ short kbuf[2][16384];  // 2 x 32KB

  const int b = blockIdx.x, qt = blockIdx.y, kt = blockIdx.z;
  const int t = threadIdx.x;
  const int wv = t >> 6, lane = t & 63, l31 = lane & 31, h = lane >> 5;

  // Q B-frags: lane = q, k = d
  bf16x8 qf[2][8];
  {
    const short* qsrc = Qs + (size_t)(b * 64 + qt * 8 + wv) * 8192;
    #pragma unroll
    for (int nq = 0; nq < 2; ++nq)
      #pragma unroll
      for (int c = 0; c < 8; ++c)
        qf[nq][c] = *(const bf16x8*)&qsrc[(2 * c + h) * 512 + (nq * 32 + l31) * 8];
  }
  float rs2[2] = {0.f, 0.f};

  const char* kbase = (const char*)(Ks + (size_t)(b * 64 + kt * 8) * 8192);
  #define STAGE2(it_, bf_)                                                      \
    { const char* src_ = kbase + (size_t)(it_) * 32768;                         \
      _Pragma("unroll")                                                         \
      for (int i_ = 0; i_ < 4; ++i_) {                                          \
        int p_ = wv * 4 + i_;                                                   \
        gll16(src_ + p_ * 1024 + lane * 16, (char*)kbuf[bf_] + p_ * 1024);      \
      } }

  STAGE2(0, 0);
  __syncthreads();

  for (int it = 0; it < 4; ++it) {
    const int cur = it & 1;
    if (it < 3) STAGE2(it + 1, cur ^ 1);
    #pragma unroll
    for (int mk = 0; mk < 4; ++mk) {
      const int kb0 = (mk >> 1) * 8192 + ((mk & 1) * 32 + l31) * 8;
      f32x16 s0 = {}, s1 = {};
      #pragma unroll
      for (int c = 0; c < 8; ++c) {  // kf loaded per-c: low register residency
        bf16x8 kf = *(const bf16x8*)&kbuf[cur][kb0 + (2 * c + h) * 512];
        s0 = __builtin_amdgcn_mfma_f32_32x32x16_bf16(kf, qf[0][c], s0, 0, 0, 0);
        s1 = __builtin_amdgcn_mfma_f32_32x32x16_bf16(kf, qf[1][c], s1, 0, 0, 0);
      }
      #pragma unroll
      for (int r = 0; r < 16; ++r) rs2[0] += __builtin_amdgcn_exp2f(s0[r]);
      #pragma unroll
      for (int r = 0; r < 16; ++r) rs2[1] += __builtin_amdgcn_exp2f(s1[r]);
    }
    __syncthreads();
  }

  #pragma unroll
  for (int nq = 0; nq < 2; ++nq) {
    float v = rs2[nq] + __shfl_xor(rs2[nq], 32, 64);
    if (h == 0)
      lpart[((size_t)kt * 8 + b) * 4096 + qt * 512 + wv * 64 + nq * 32 + l31] = v;
  }
}

// ---------------- Phase B: gpart[b,qt,kt][k] = sum_q linv[q] exp(S) ----------------
// Same shape. linv folded as log2 into the MFMA accumulator init (no li registers):
// sc = ladj[q] + log2e*q.k  ->  gp += exp2(sc).
__global__ __launch_bounds__(512, 4) void attnv_kernel(
    const short* __restrict__ Qs, const short* __restrict__ Ks,
    const float* __restrict__ lpart, float* __restrict__ gpart) {
  __shared__ short kbuf[2][8192];   // 2 x 16KB
  __shared__ float ladj_lds[512];
  __shared__ float gw[8][512];      // 16KB

  const int b = blockIdx.x, qt = blockIdx.y, kt = blockIdx.z;
  const int t = threadIdx.x;
  const int wv = t >> 6, lane = t & 63, l31 = lane & 31, h = lane >> 5;

  {  // ladj[q] = log2(linv[q]) = -(log2(l) + 12)
    int q = qt * 512 + t;
    float l = 0.f;
    #pragma unroll
    for (int k2 = 0; k2 < 8; ++k2) l += lpart[((size_t)k2 * 8 + b) * 4096 + q];
    ladj_lds[t] = -(__builtin_amdgcn_logf(l) + 12.0f);
  }

  bf16x8 qf[2][8];  // A-frags: lane = q-row
  {
    const short* qsrc = Qs + (size_t)(b * 64 + qt * 8 + wv) * 8192;
    #pragma unroll
    for (int mq = 0; mq < 2; ++mq)
      #pragma unroll
      for (int c = 0; c < 8; ++c)
        qf[mq][c] = *(const bf16x8*)&qsrc[(2 * c + h) * 512 + (mq * 32 + l31) * 8];
  }
  __syncthreads();  // ladj ready

  const char* kbase = (const char*)(Ks + (size_t)(b * 64 + kt * 8) * 8192);
  #define STAGE1(it_, bf_)                                                      \
    { const char* src_ = kbase + (size_t)(it_) * 16384;                         \
      _Pragma("unroll")                                                         \
      for (int i_ = 0; i_ < 2; ++i_) {                                          \
        int p_ = wv * 2 + i_;                                                   \
        gll16(src_ + p_ * 1024 + lane * 16, (char*)kbuf[bf_] + p_ * 1024);      \
      } }

  STAGE1(0, 0);
  __syncthreads();

  for (int it = 0; it < 8; ++it) {
    const int cur = it & 1;
    if (it < 7) STAGE1(it + 1, cur ^ 1);
    #pragma unroll
    for (int nk = 0; nk < 2; ++nk) {
      const int kb0 = (nk * 32 + l31) * 8;
      float gp = 0.f;
      #pragma unroll
      for (int nq = 0; nq < 2; ++nq) {  // sequential chains: acc <= 16 live
        f32x16 sc;
        #pragma unroll
        for (int r = 0; r < 16; ++r)  // re-read each iter (cheap broadcast; no hoist)
          sc[r] = ladj_lds[wv * 64 + nq * 32 + (r & 3) + 8 * (r >> 2) + 4 * h];
        #pragma unroll
        for (int c = 0; c < 8; ++c) {
          bf16x8 kf = *(const bf16x8*)&kbuf[cur][kb0 + (2 * c + h) * 512];
          sc = __builtin_amdgcn_mfma_f32_32x32x16_bf16(qf[nq][c], kf, sc, 0, 0, 0);
        }
        #pragma unroll
        for (int r = 0; r < 16; ++r) gp += __builtin_amdgcn_exp2f(sc[r]);
      }
      gp += __shfl_xor(gp, 32, 64);
      if (h == 0) gw[wv][it * 64 + nk * 32 + l31] = gp;
    }
    __syncthreads();
  }

  float s = 0.f;
  #pragma unroll
  for (int w2 = 0; w2 < 8; ++w2) s += gw[w2][t];
  gpart[(((size_t)(b * 8 + qt) * 8) + kt) * 512 + t] = s;
}

// ---------------- GEMV: out[b,d] = sum_k G[b,k] V[k,d] ----------------
__global__ __launch_bounds__(256) void gemv_kernel(
    const float* __restrict__ gpart, const short* __restrict__ Vp,
    float* __restrict__ out) {
  __shared__ float Gs[128];
  __shared__ float pwb[512];
  const int b = blockIdx.x, ks = blockIdx.y;
  const int t = threadIdx.x;
  if (t < 128) {
    int k = ks * 128 + t;
    int kt = k >> 9, kl = k & 511;
    float s = 0.f;
    #pragma unroll
    for (int qt = 0; qt < 8; ++qt)
      s += gpart[(((size_t)(b * 8 + qt) * 8) + kt) * 512 + kl];
    Gs[t] = s;
  }
  __syncthreads();
  const int dp = t & 63, kq = t >> 6;
  const short* vr = Vp + ((size_t)b * 4096 + ks * 128 + kq * 32) * 128 + 2 * dp;
  float a0 = 0.f, a1 = 0.f;
  #pragma unroll 8
  for (int k = 0; k < 32; ++k) {
    u32 pair = *(const u32*)&vr[(size_t)k * 128];
    float g = Gs[kq * 32 + k];
    a0 += g * __uint_as_float(pair << 16);
    a1 += g * __uint_as_float(pair & 0xffff0000u);
  }
  pwb[kq * 128 + 2 * dp] = a0;
  pwb[kq * 128 + 2 * dp + 1] = a1;
  __syncthreads();
  if (t < 128) {
    float s = (pwb[t] + pwb[128 + t]) + (pwb[256 + t] + pwb[384 + t]);
    atomicAdd(&out[b * 128 + t], s);
  }
}

extern "C" void kernel_launch(void* const* d_in, const int* in_sizes, int n_in,
                              void* d_out, int out_size, void* d_ws, size_t ws_size,
                              hipStream_t stream) {
  const float* x = (const float*)d_in[0];  // fp32 [8,4096,128]
  const float* w = (const float*)d_in[1];  // fp32 [3,128,128]
  short* Qs = (short*)d_ws;                               // 8MB bf16 staged
  short* Ks = Qs + (size_t)Bsz * Ssz * Dsz;               // 8MB staged
  short* Vp = Ks + (size_t)Bsz * Ssz * Dsz;               // 8MB row-major
  float* lpart = (float*)(Vp + (size_t)Bsz * Ssz * Dsz);  // 1MB [kt8][b8][q4096]
  float* gpart = lpart + 8 * Bsz * Ssz;                   // 2MB [b8][qt8][kt8][k512]

  proj_kernel<<<dim3(Bsz * Ssz / 64), dim3(256), 0, stream>>>(x, w, Qs, Ks, Vp,
                                                              (float*)d_out);
  lsum_kernel<<<dim3(Bsz, 8, 8), dim3(512), 0, stream>>>(Qs, Ks, lpart);
  attnv_kernel<<<dim3(Bsz, 8, 8), dim3(512), 0, stream>>>(Qs, Ks, lpart, gpart);
  gemv_kernel<<<dim3(Bsz, 32), dim3(256), 0, stream>>>(gpart, Vp, (float*)d_out);
}